// Round 4
// baseline (75.560 us; speedup 1.0000x reference)
//
#include <hip/hip_runtime.h>

// Problem constants (match reference)
constexpr int Bn = 4, Dn = 128, Hn = 128, Wn = 128, Cn = 16;
constexpr int NPIX = Hn * Wn;  // 16384
constexpr int PS = 4;          // pixel chunks per (b,d) in k_proto

// ws layout (floats):
//   protoPart [Bn][PS][Cn][Dn]  = 32768
//   countsPart[Bn][PS][Cn]      = 256
//   maskPart  [Bn][PS]          = 16
//   cePart    [512]             (k_main grid)
// All written with plain stores every call (no zero-init, no global atomics).

// ---------------------------------------------------------------------------
// K1: per-(b,d,chunk) prototype partial sums via LDS float atomics into
// per-(wave, 16-lane-group) class accumulators: sacc[wid][g][c].
// Avg 1 lane per (g,c) -> minimal same-address serialization; 64 distinct
// words -> 2-way bank alias (free). d==0 blocks also do label counts (LDS
// int atomics) and mask sum. grid = Bn*Dn*PS = 2048 blocks, 256 threads.
// ---------------------------------------------------------------------------
__global__ void k_proto(const float* __restrict__ x,
                        const int* __restrict__ label,
                        const int* __restrict__ mask,
                        float* __restrict__ protoPart,   // [Bn][PS][Cn][Dn]
                        float* __restrict__ countsPart,  // [Bn][PS][Cn]
                        float* __restrict__ maskPart) {  // [Bn][PS]
    int bid = blockIdx.x;
    int chunk = bid & (PS - 1);
    int d = (bid >> 2) & (Dn - 1);
    int b = bid >> 9;               // Dn*PS = 512 blocks per batch
    int tid = threadIdx.x;
    int wid = tid >> 6, lane = tid & 63, g = lane >> 4;

    __shared__ float sacc[4][4][Cn];   // [wave][lane-group][class], 1 KB
    __shared__ int   scnt[4][Cn];      // [wave][class], d==0 blocks only
    ((float*)sacc)[tid] = 0.f;         // 256 entries == blockDim
    if (tid < 64) ((int*)scnt)[tid] = 0;
    __syncthreads();

    constexpr int CH = NPIX / PS;      // 4096 pixels per block
    const float4* xp = (const float4*)(x + (size_t)(b * Dn + d) * NPIX + chunk * CH);
    const int4*   lp = (const int4*)(label + (size_t)b * NPIX + chunk * CH);

    float* myacc = &sacc[wid][g][0];
    if (d == 0) {
        int* mycnt = &scnt[wid][0];
        for (int i = tid; i < CH / 4; i += 256) {   // 4 iterations
            float4 xv = xp[i];
            int4 lv = lp[i];
            int l0 = lv.x - 1, l1 = lv.y - 1, l2 = lv.z - 1, l3 = lv.w - 1;
            atomicAdd(&myacc[l0], xv.x);  atomicAdd(&mycnt[l0], 1);
            atomicAdd(&myacc[l1], xv.y);  atomicAdd(&mycnt[l1], 1);
            atomicAdd(&myacc[l2], xv.z);  atomicAdd(&mycnt[l2], 1);
            atomicAdd(&myacc[l3], xv.w);  atomicAdd(&mycnt[l3], 1);
        }
    } else {
        for (int i = tid; i < CH / 4; i += 256) {
            float4 xv = xp[i];
            int4 lv = lp[i];
            atomicAdd(&myacc[lv.x - 1], xv.x);
            atomicAdd(&myacc[lv.y - 1], xv.y);
            atomicAdd(&myacc[lv.z - 1], xv.z);
            atomicAdd(&myacc[lv.w - 1], xv.w);
        }
    }
    __syncthreads();

    if (tid < Cn) {
        float s = 0.f;
#pragma unroll
        for (int w = 0; w < 4; ++w)
#pragma unroll
            for (int gg = 0; gg < 4; ++gg) s += sacc[w][gg][tid];
        protoPart[(((size_t)b * PS + chunk) * Cn + tid) * Dn + d] = s;
        if (d == 0) {
            int ct = scnt[0][tid] + scnt[1][tid] + scnt[2][tid] + scnt[3][tid];
            countsPart[((size_t)b * PS + chunk) * Cn + tid] = (float)ct;
        }
    }

    if (d == 0) {   // block-uniform: mask sum for this chunk
        int msum = 0;
        const int4* mp = (const int4*)(mask + (size_t)b * NPIX + chunk * CH);
        for (int i = tid; i < CH / 4; i += 256) {
            int4 mv = mp[i];
            msum += mv.x + mv.y + mv.z + mv.w;
        }
        for (int off = 32; off; off >>= 1) msum += __shfl_down(msum, off);
        __shared__ int mred[4];
        if (lane == 0) mred[wid] = msum;
        __syncthreads();
        if (tid == 0)
            maskPart[b * PS + chunk] = (float)(mred[0] + mred[1] + mred[2] + mred[3]);
    }
}

// ---------------------------------------------------------------------------
// K2: metric + CE. Block = 256 threads covers 128 pixels; wave w handles
// d in [32w, 32w+32) for 2 pixels/thread (float2 x loads; proto q-regs
// amortized over the pixel pair -> half the ds_read_b128 per pixel).
// grid = Bn * (NPIX/128) = 512 blocks.
// ---------------------------------------------------------------------------
__global__ void k_main(const float* __restrict__ x,
                       const int* __restrict__ label,
                       const int* __restrict__ mask,
                       const float* __restrict__ protoPart,
                       const float* __restrict__ countsPart,
                       float* __restrict__ cePart) { // [512]
    int b = blockIdx.x >> 7;                 // 128 blocks per batch
    int pbase = (blockIdx.x & 127) << 7;     // 128 pixels per block
    int tid = threadIdx.x;
    int lx = tid & 63, dg = tid >> 6;        // dg in 0..3
    int wid = dg, lane = lx;

    __shared__ float cntInv[Cn];
    __shared__ float proto[Dn][Cn];          // 8 KB, [d][c]
    __shared__ float part[4][Cn][128];       // 32 KB

    if (tid < Cn) {
        float s = 0.f;
#pragma unroll
        for (int ch = 0; ch < PS; ++ch)
            s += countsPart[((size_t)b * PS + ch) * Cn + tid];
        cntInv[tid] = 1.f / s;
    }
    __syncthreads();
    for (int i = tid; i < Cn * Dn; i += 256) {
        int c = i >> 7;
        int d = i & (Dn - 1);
        float s = 0.f;
#pragma unroll
        for (int ch = 0; ch < PS; ++ch)
            s += protoPart[(((size_t)b * PS + ch) * Cn + c) * Dn + d];
        proto[d][c] = s * cntInv[c];
    }
    __syncthreads();

    float2 acc[Cn];
#pragma unroll
    for (int c = 0; c < Cn; ++c) acc[c] = make_float2(0.f, 0.f);

    const float2* xp = (const float2*)(x + (size_t)b * Dn * NPIX + pbase) + lx;
#pragma unroll 4
    for (int dd = 0; dd < 32; ++dd) {
        int d = (dg << 5) + dd;
        float2 xv = xp[(size_t)d * (NPIX / 2)];
        float4 q0 = *(const float4*)&proto[d][0];
        float4 q1 = *(const float4*)&proto[d][4];
        float4 q2 = *(const float4*)&proto[d][8];
        float4 q3 = *(const float4*)&proto[d][12];
        acc[0].x  += fabsf(xv.x - q0.x);  acc[0].y  += fabsf(xv.y - q0.x);
        acc[1].x  += fabsf(xv.x - q0.y);  acc[1].y  += fabsf(xv.y - q0.y);
        acc[2].x  += fabsf(xv.x - q0.z);  acc[2].y  += fabsf(xv.y - q0.z);
        acc[3].x  += fabsf(xv.x - q0.w);  acc[3].y  += fabsf(xv.y - q0.w);
        acc[4].x  += fabsf(xv.x - q1.x);  acc[4].y  += fabsf(xv.y - q1.x);
        acc[5].x  += fabsf(xv.x - q1.y);  acc[5].y  += fabsf(xv.y - q1.y);
        acc[6].x  += fabsf(xv.x - q1.z);  acc[6].y  += fabsf(xv.y - q1.z);
        acc[7].x  += fabsf(xv.x - q1.w);  acc[7].y  += fabsf(xv.y - q1.w);
        acc[8].x  += fabsf(xv.x - q2.x);  acc[8].y  += fabsf(xv.y - q2.x);
        acc[9].x  += fabsf(xv.x - q2.y);  acc[9].y  += fabsf(xv.y - q2.y);
        acc[10].x += fabsf(xv.x - q2.z);  acc[10].y += fabsf(xv.y - q2.z);
        acc[11].x += fabsf(xv.x - q2.w);  acc[11].y += fabsf(xv.y - q2.w);
        acc[12].x += fabsf(xv.x - q3.x);  acc[12].y += fabsf(xv.y - q3.x);
        acc[13].x += fabsf(xv.x - q3.y);  acc[13].y += fabsf(xv.y - q3.y);
        acc[14].x += fabsf(xv.x - q3.z);  acc[14].y += fabsf(xv.y - q3.z);
        acc[15].x += fabsf(xv.x - q3.w);  acc[15].y += fabsf(xv.y - q3.w);
    }

#pragma unroll
    for (int c = 0; c < Cn; ++c)
        *(float2*)&part[dg][c][lx * 2] = acc[c];
    __syncthreads();

    float v = 0.f;
    if (tid < 128) {   // 2 waves handle the 128-pixel epilogue
        float a[Cn];
#pragma unroll
        for (int c = 0; c < Cn; ++c)
            a[c] = part[0][c][tid] + part[1][c][tid] + part[2][c][tid] + part[3][c][tid];

        float pd0[Cn];
        float mn = 3.4e38f;
#pragma unroll
        for (int c = 0; c < Cn; ++c) {
            pd0[c] = __expf(-a[c]);
            mn = fminf(mn, pd0[c]);
        }
        float se = 0.f;
#pragma unroll
        for (int c = 0; c < Cn; ++c) se += __expf(pd0[c] - mn);

        int p = pbase + tid;
        int l = label[b * NPIX + p] - 1;
        float pdl = 0.f;
#pragma unroll
        for (int c = 0; c < Cn; ++c) pdl = (l == c) ? (pd0[c] - mn) : pdl;

        float ce = __logf(se) - pdl;
        float m = (float)mask[b * NPIX + p];
        v = ce * m;
    }
    for (int off = 32; off; off >>= 1) v += __shfl_down(v, off);
    __shared__ float r2[4];
    if (lane == 0) r2[wid] = v;
    __syncthreads();
    if (tid == 0) cePart[blockIdx.x] = r2[0] + r2[1] + r2[2] + r2[3];
}

// ---------------------------------------------------------------------------
// K3: final combine. 1 block, 256 threads; wave w reduces batch w.
// ---------------------------------------------------------------------------
__global__ void k_final(const float* __restrict__ cePart,   // [Bn][128]
                        const float* __restrict__ maskPart, // [Bn][PS]
                        float* __restrict__ out) {
    int tid = threadIdx.x;
    int w = tid >> 6, lane = tid & 63;

    float s = cePart[w * 128 + lane] + cePart[w * 128 + lane + 64];
    for (int off = 32; off; off >>= 1) s += __shfl_down(s, off);

    __shared__ float r[4];
    if (lane == 0) {
        float ms = maskPart[w * PS + 0] + maskPart[w * PS + 1]
                 + maskPart[w * PS + 2] + maskPart[w * PS + 3];
        r[w] = s / ms;
    }
    __syncthreads();
    if (tid == 0) out[0] = r[0] + r[1] + r[2] + r[3];
}

extern "C" void kernel_launch(void* const* d_in, const int* in_sizes, int n_in,
                              void* d_out, int out_size, void* d_ws, size_t ws_size,
                              hipStream_t stream) {
    const float* x     = (const float*)d_in[0];  // [B,D,H,W] f32
    const int*   label = (const int*)d_in[1];    // [B,H,W]
    const int*   mask  = (const int*)d_in[2];    // [B,1,H,W]
    float* out = (float*)d_out;

    float* ws         = (float*)d_ws;
    float* protoPart  = ws;                               // 32768
    float* countsPart = protoPart + Bn * PS * Cn * Dn;    // 256
    float* maskPart   = countsPart + Bn * PS * Cn;        // 16
    float* cePart     = maskPart + Bn * PS;               // 512

    k_proto<<<Bn * Dn * PS, 256, 0, stream>>>(x, label, mask,
                                              protoPart, countsPart, maskPart);
    k_main <<<Bn * (NPIX / 128), 256, 0, stream>>>(x, label, mask,
                                                   protoPart, countsPart, cePart);
    k_final<<<1, 256, 0, stream>>>(cePart, maskPart, out);
}

// Round 5
// 44.381 us; speedup vs baseline: 1.7025x; 1.7025x over previous
//
#include <hip/hip_runtime.h>

// Problem constants (match reference)
constexpr int Bn = 4, Dn = 128, Hn = 128, Wn = 128, Cn = 16;
constexpr int NPIX = Hn * Wn;  // 16384
constexpr int PS = 2;          // pixel chunks per (b,d) in k_proto

// ws layout (floats), all plain stores, no zero-init, no global atomics:
//   protoPart [Bn][PS][Cn][Dn] = 16384
//   countsPart[Bn][PS][Cn]     = 128
//   maskPart  [Bn][PS]         = 8
//   cePart    [Bn*256]         = 1024
//   protoF    [Bn][Dn][Cn]     = 8192   (finalized proto/count, 64B rows)

// ---------------------------------------------------------------------------
// K1: per-(b,d,chunk) prototype partial sums, predicated cndmask accumulate
// (VALU-bound ~5 us). d==0 blocks also compute label counts via ballot/popc
// (SGPR accumulators) + mask sum in an epilogue pass.
// grid = Bn*Dn*PS = 1024 blocks, 256 threads -> 4 blocks/CU, 16 waves/CU.
// ---------------------------------------------------------------------------
__global__ __launch_bounds__(256) void k_proto(
        const float* __restrict__ x,
        const int* __restrict__ label,
        const int* __restrict__ mask,
        float* __restrict__ protoPart,   // [Bn][PS][Cn][Dn]
        float* __restrict__ countsPart,  // [Bn][PS][Cn]
        float* __restrict__ maskPart) {  // [Bn][PS]
    int bid = blockIdx.x;
    int chunk = bid & (PS - 1);
    int d = (bid >> 1) & (Dn - 1);
    int b = bid >> 8;               // Dn*PS = 256 blocks per batch
    int tid = threadIdx.x;
    int wid = tid >> 6, lane = tid & 63;

    constexpr int CH = NPIX / PS;   // 8192 pixels per block
    const float4* xp = (const float4*)(x + (size_t)(b * Dn + d) * NPIX + chunk * CH);
    const int4*   lp = (const int4*)(label + (size_t)b * NPIX + chunk * CH);

    float acc[Cn];
#pragma unroll
    for (int c = 0; c < Cn; ++c) acc[c] = 0.f;

#pragma unroll 4
    for (int i = tid; i < CH / 4; i += 256) {   // 8 iterations
        float4 xv = xp[i];
        int4 lv = lp[i];
        int l0 = lv.x - 1, l1 = lv.y - 1, l2 = lv.z - 1, l3 = lv.w - 1;
#pragma unroll
        for (int c = 0; c < Cn; ++c) {
            acc[c] += ((l0 == c) ? xv.x : 0.f) + ((l1 == c) ? xv.y : 0.f)
                    + ((l2 == c) ? xv.z : 0.f) + ((l3 == c) ? xv.w : 0.f);
        }
    }

#pragma unroll
    for (int c = 0; c < Cn; ++c)
        for (int off = 32; off; off >>= 1) acc[c] += __shfl_down(acc[c], off);

    __shared__ float red[4][Cn];
    if (lane == 0) {
#pragma unroll
        for (int c = 0; c < Cn; ++c) red[wid][c] = acc[c];
    }
    __syncthreads();
    if (tid < Cn) {
        float s = red[0][tid] + red[1][tid] + red[2][tid] + red[3][tid];
        protoPart[(((size_t)b * PS + chunk) * Cn + tid) * Dn + d] = s;
    }

    if (d == 0) {
        // counts via ballot/popc: accumulators are wave-uniform -> SGPRs
        int cnt[Cn];
#pragma unroll
        for (int c = 0; c < Cn; ++c) cnt[c] = 0;
        int msum = 0;
        const int4* mp = (const int4*)(mask + (size_t)b * NPIX + chunk * CH);
        for (int i = tid; i < CH / 4; i += 256) {
            int4 lv = lp[i];
            int4 mv = mp[i];
            msum += mv.x + mv.y + mv.z + mv.w;
            int l0 = lv.x - 1, l1 = lv.y - 1, l2 = lv.z - 1, l3 = lv.w - 1;
#pragma unroll
            for (int c = 0; c < Cn; ++c) {
                cnt[c] += (int)__popcll(__ballot(l0 == c))
                        + (int)__popcll(__ballot(l1 == c))
                        + (int)__popcll(__ballot(l2 == c))
                        + (int)__popcll(__ballot(l3 == c));
            }
        }
        for (int off = 32; off; off >>= 1) msum += __shfl_down(msum, off);

        __shared__ int redi[4][Cn + 1];
        if (lane == 0) {
#pragma unroll
            for (int c = 0; c < Cn; ++c) redi[wid][c] = cnt[c];
            redi[wid][Cn] = msum;
        }
        __syncthreads();
        if (tid < Cn) {
            int s = redi[0][tid] + redi[1][tid] + redi[2][tid] + redi[3][tid];
            countsPart[((size_t)b * PS + chunk) * Cn + tid] = (float)s;
        } else if (tid == Cn) {
            int s = redi[0][Cn] + redi[1][Cn] + redi[2][Cn] + redi[3][Cn];
            maskPart[b * PS + chunk] = (float)s;
        }
    }
}

// ---------------------------------------------------------------------------
// K2: finalize protoF[b][d][c] = protoSum / count. 8192 outputs.
// grid = 32 blocks, 256 threads. Tiny.
// ---------------------------------------------------------------------------
__global__ void k_reduce(const float* __restrict__ protoPart,
                         const float* __restrict__ countsPart,
                         float* __restrict__ protoF) { // [Bn][Dn][Cn]
    int idx = blockIdx.x * 256 + threadIdx.x;   // (b*Dn + d)*Cn + c
    int c = idx & (Cn - 1);
    int d = (idx >> 4) & (Dn - 1);
    int b = idx >> 11;
    float s = 0.f, cs = 0.f;
#pragma unroll
    for (int ch = 0; ch < PS; ++ch) {
        s  += protoPart[(((size_t)b * PS + ch) * Cn + c) * Dn + d];
        cs += countsPart[((size_t)b * PS + ch) * Cn + c];
    }
    protoF[idx] = s / cs;
}

// ---------------------------------------------------------------------------
// K3: metric + CE. 512-thread blocks (8 waves); wave w handles d in
// [16w, 16w+16) for 64 pixels. Proto rows read through wave-uniform
// addresses (readfirstlane) -> scalar/L1-broadcast loads, NO LDS broadcast.
// grid = Bn*256 = 1024 blocks -> 4 blocks/CU, 32 waves/CU.
// ---------------------------------------------------------------------------
__global__ __launch_bounds__(512, 6) void k_main(
        const float* __restrict__ x,
        const int* __restrict__ label,
        const int* __restrict__ mask,
        const float* __restrict__ protoF,  // [Bn][Dn][Cn]
        float* __restrict__ cePart) {      // [Bn*256]
    int b = blockIdx.x >> 8;                 // 256 blocks per batch
    int pbase = (blockIdx.x & 255) << 6;     // 64 pixels per block
    int tid = threadIdx.x;
    int w = tid >> 6, lane = tid & 63;
    int wu = __builtin_amdgcn_readfirstlane(w);   // wave-uniform wave id

    __shared__ float part[8][Cn][64];        // 32 KB

    float acc[Cn];
#pragma unroll
    for (int c = 0; c < Cn; ++c) acc[c] = 0.f;

    const float* xp = x + (size_t)b * Dn * NPIX + pbase + lane;
    const float* pf = protoF + ((size_t)b * Dn + (wu << 4)) * Cn;

#pragma unroll 2
    for (int dd = 0; dd < 16; ++dd) {
        int d = (wu << 4) + dd;
        float xv = xp[(size_t)d * NPIX];
        const float4* prow = (const float4*)(pf + dd * Cn);  // uniform addr
        float4 q0 = prow[0];
        float4 q1 = prow[1];
        float4 q2 = prow[2];
        float4 q3 = prow[3];
        acc[0]  += fabsf(xv - q0.x);  acc[1]  += fabsf(xv - q0.y);
        acc[2]  += fabsf(xv - q0.z);  acc[3]  += fabsf(xv - q0.w);
        acc[4]  += fabsf(xv - q1.x);  acc[5]  += fabsf(xv - q1.y);
        acc[6]  += fabsf(xv - q1.z);  acc[7]  += fabsf(xv - q1.w);
        acc[8]  += fabsf(xv - q2.x);  acc[9]  += fabsf(xv - q2.y);
        acc[10] += fabsf(xv - q2.z);  acc[11] += fabsf(xv - q2.w);
        acc[12] += fabsf(xv - q3.x);  acc[13] += fabsf(xv - q3.y);
        acc[14] += fabsf(xv - q3.z);  acc[15] += fabsf(xv - q3.w);
    }

#pragma unroll
    for (int c = 0; c < Cn; ++c) part[w][c][lane] = acc[c];
    __syncthreads();

    if (tid < 64) {   // one wave: epilogue for the block's 64 pixels
        float a[Cn];
#pragma unroll
        for (int c = 0; c < Cn; ++c) {
            float s = 0.f;
#pragma unroll
            for (int ww = 0; ww < 8; ++ww) s += part[ww][c][tid];
            a[c] = s;
        }

        float pd0[Cn];
        float mn = 3.4e38f;
#pragma unroll
        for (int c = 0; c < Cn; ++c) {
            pd0[c] = __expf(-a[c]);
            mn = fminf(mn, pd0[c]);
        }
        float se = 0.f;
#pragma unroll
        for (int c = 0; c < Cn; ++c) se += __expf(pd0[c] - mn);

        int p = pbase + tid;
        int l = label[b * NPIX + p] - 1;
        float pdl = 0.f;
#pragma unroll
        for (int c = 0; c < Cn; ++c) pdl = (l == c) ? (pd0[c] - mn) : pdl;

        float ce = __logf(se) - pdl;
        float m = (float)mask[b * NPIX + p];
        float v = ce * m;

        for (int off = 32; off; off >>= 1) v += __shfl_down(v, off);
        if (tid == 0) cePart[blockIdx.x] = v;
    }
}

// ---------------------------------------------------------------------------
// K4: final combine. 1 block, 256 threads; wave w reduces batch w.
// ---------------------------------------------------------------------------
__global__ void k_final(const float* __restrict__ cePart,   // [Bn][256]
                        const float* __restrict__ maskPart, // [Bn][PS]
                        float* __restrict__ out) {
    int tid = threadIdx.x;
    int w = tid >> 6, lane = tid & 63;

    float s = cePart[w * 256 + lane]       + cePart[w * 256 + lane + 64]
            + cePart[w * 256 + lane + 128] + cePart[w * 256 + lane + 192];
    for (int off = 32; off; off >>= 1) s += __shfl_down(s, off);

    __shared__ float r[4];
    if (lane == 0) {
        float ms = 0.f;
#pragma unroll
        for (int ch = 0; ch < PS; ++ch) ms += maskPart[w * PS + ch];
        r[w] = s / ms;
    }
    __syncthreads();
    if (tid == 0) out[0] = r[0] + r[1] + r[2] + r[3];
}

extern "C" void kernel_launch(void* const* d_in, const int* in_sizes, int n_in,
                              void* d_out, int out_size, void* d_ws, size_t ws_size,
                              hipStream_t stream) {
    const float* x     = (const float*)d_in[0];  // [B,D,H,W] f32
    const int*   label = (const int*)d_in[1];    // [B,H,W]
    const int*   mask  = (const int*)d_in[2];    // [B,1,H,W]
    float* out = (float*)d_out;

    float* ws         = (float*)d_ws;
    float* protoPart  = ws;                               // 16384
    float* countsPart = protoPart + Bn * PS * Cn * Dn;    // 128
    float* maskPart   = countsPart + Bn * PS * Cn;        // 8
    float* cePart     = maskPart + Bn * PS;               // 1024
    float* protoF     = cePart + Bn * 256;                // 8192 (64B-aligned)

    k_proto <<<Bn * Dn * PS, 256, 0, stream>>>(x, label, mask,
                                               protoPart, countsPart, maskPart);
    k_reduce<<<Bn * Dn * Cn / 256, 256, 0, stream>>>(protoPart, countsPart, protoF);
    k_main  <<<Bn * 256, 512, 0, stream>>>(x, label, mask, protoF, cePart);
    k_final <<<1, 256, 0, stream>>>(cePart, maskPart, out);
}